// Round 13
// baseline (20.198 us; speedup 1.0000x reference)
//
#include <hip/hip_runtime.h>
#include <math.h>

#define NB 4096
#define ND 128
#define TT 256        // tile size; K = ND = 128 staged whole
#define NT (NB / TT)  // 16 tiles per dimension; grid = 256 = 1 block/CU

typedef __bf16 bf16x8 __attribute__((ext_vector_type(8)));
typedef float  f32x4  __attribute__((ext_vector_type(4)));

// DPP-based sum over each 16-lane row group (pure VALU, no DS pipe).
// Steps: quad pairs (0xB1), quads (0x4E), +quad(q+1) (row_ror:4), +pair of
// far quads (row_ror:8). Bit-identical per (row, lane-slot) across blocks.
__device__ __forceinline__ float dpp_add16(float x) {
    int y;
    y = __builtin_amdgcn_update_dpp(0, __float_as_int(x), 0xB1, 0xF, 0xF, true);
    x += __int_as_float(y);
    y = __builtin_amdgcn_update_dpp(0, __float_as_int(x), 0x4E, 0xF, 0xF, true);
    x += __int_as_float(y);
    y = __builtin_amdgcn_update_dpp(0, __float_as_int(x), 0x124, 0xF, 0xF, true);
    x += __int_as_float(y);
    y = __builtin_amdgcn_update_dpp(0, __float_as_int(x), 0x128, 0xF, 0xF, true);
    x += __int_as_float(y);
    return x;
}

// ---- pass 1: fused normalize + 256x256 LDS sim-tile + MFMA + stats ----------
// 8 waves (512 thr): wr = wid>>1 (4 x 64 i-rows, it=4), wc = wid&1 (2 x 128
// j-cols, jt=8). LDS reads 48/wave x 8 = 384 KB/CU (was 640).
// LDS layout (16B chunks): (row, c16) -> slot row*16 + (c16 ^ (row&15)).
// Swapped MFMA operands: D col (lane&15) = i index -> stats accumulate
// in-thread; cross-lane reduce = offsets 16/32 only.
__global__ __launch_bounds__(512) void supcon_mfma(
    const float* __restrict__ f, const int* __restrict__ labels,
    f32x4* __restrict__ partials, float* __restrict__ out)
{
    __shared__ __align__(16) __bf16 At[TT * ND];   // 64 KB (i rows)
    __shared__ __align__(16) __bf16 Bt[TT * ND];   // 64 KB (j rows)
    __shared__ float redL[2][TT][3];               // 6 KB

    const int t    = threadIdx.x;
    const int lane = t & 63;
    const int wid  = t >> 6;            // 0..7
    const int wr   = wid >> 1;          // 0..3 : i rows wr*64 .. +64
    const int wc   = wid & 1;           // 0..1 : j cols wc*128 .. +128
    const int bi   = blockIdx.x >> 4;   // i tile 0..15
    const int cs   = blockIdx.x & 15;   // j tile 0..15
    const int lr   = lane & 15;
    const int lk   = lane >> 4;
    const int ib   = bi * TT;
    const int jb   = cs * TT;

    if (blockIdx.x == 0 && t == 0) out[0] = 0.f;   // target of final's atomics

    // ---- stage + normalize both tiles (f32 -> bf16, XOR-swizzled) -----------
    {
        const int c16  = t & 15;        // 16B-chunk index within row
        const int rloc = t >> 4;        // 0..31
        const float* gA = f + (size_t)ib * ND;
        const float* gB = f + (size_t)jb * ND;
#pragma unroll
        for (int s = 0; s < 2; ++s) {
            const float* g = s ? gB : gA;
            __bf16*      T = s ? Bt : At;
#pragma unroll
            for (int p = 0; p < 8; ++p) {
                const int row = p * 32 + rloc;
                const float4 lo = *reinterpret_cast<const float4*>(g + row * ND + c16 * 8);
                const float4 hi = *reinterpret_cast<const float4*>(g + row * ND + c16 * 8 + 4);
                float ss = lo.x*lo.x + lo.y*lo.y + lo.z*lo.z + lo.w*lo.w
                         + hi.x*hi.x + hi.y*hi.y + hi.z*hi.z + hi.w*hi.w;
                ss = dpp_add16(ss);     // VALU reduction across the 16 lanes
                const float inv = 1.0f / fmaxf(sqrtf(ss), 1e-12f);
                bf16x8 o;
                o[0] = (__bf16)(lo.x * inv); o[1] = (__bf16)(lo.y * inv);
                o[2] = (__bf16)(lo.z * inv); o[3] = (__bf16)(lo.w * inv);
                o[4] = (__bf16)(hi.x * inv); o[5] = (__bf16)(hi.y * inv);
                o[6] = (__bf16)(hi.z * inv); o[7] = (__bf16)(hi.w * inv);
                *reinterpret_cast<bf16x8*>(&T[(row * 16 + (c16 ^ (row & 15))) * 8]) = o;
            }
        }
    }

    // my i indices / labels (overlap staging latency)
    int ig[4], labi[4];
#pragma unroll
    for (int it = 0; it < 4; ++it) {
        ig[it]   = ib + wr * 64 + it * 16 + lr;   // D col = lane&15
        labi[it] = labels[ig[it]];
    }

    __syncthreads();

    // preload i-side fragments (MFMA B operand)
    bf16x8 bfr[4][4];
#pragma unroll
    for (int it = 0; it < 4; ++it)
#pragma unroll
        for (int ks = 0; ks < 4; ++ks) {
            const int row = wr * 64 + it * 16 + lr;
            bfr[it][ks] = *reinterpret_cast<const bf16x8*>(
                &At[(row * 16 + ((ks * 4 + lk) ^ lr)) * 8]);
        }

    float es[4] = {}, ps[4] = {}, np[4] = {};

#pragma unroll
    for (int jt = 0; jt < 8; ++jt) {
        // j-side fragments (MFMA A operand)
        bf16x8 af[4];
#pragma unroll
        for (int ks = 0; ks < 4; ++ks) {
            const int row = wc * 128 + jt * 16 + lr;
            af[ks] = *reinterpret_cast<const bf16x8*>(
                &Bt[(row * 16 + ((ks * 4 + lk) ^ lr)) * 8]);
        }
        f32x4 acc[4] = {};
#pragma unroll
        for (int ks = 0; ks < 4; ++ks)
#pragma unroll
            for (int it = 0; it < 4; ++it)
                acc[it] = __builtin_amdgcn_mfma_f32_16x16x32_bf16(
                    af[ks], bfr[it][ks], acc[it], 0, 0, 0);

        // j labels for this 16-tile: contiguous int4 per lk group
        const int jg0 = jb + wc * 128 + jt * 16 + lk * 4;   // D row = lk*4 + r
        const int4 lj4 = *reinterpret_cast<const int4*>(&labels[jg0]);
        const int lj[4] = {lj4.x, lj4.y, lj4.z, lj4.w};

        // epilogue: D[row = j-local = lk*4+r][col = i-local = lr]
#pragma unroll
        for (int it = 0; it < 4; ++it)
#pragma unroll
            for (int r = 0; r < 4; ++r) {
                const int   jgv  = jg0 + r;
                const float s    = acc[it][r];
                const float e    = __expf(s);
                const bool  self = (jgv == ig[it]);
                const bool  pos  = (lj[r] == labi[it]) && !self;
                es[it] += self ? 0.f : e;
                ps[it] += pos ? s : 0.f;
                np[it] += pos ? 1.f : 0.f;
            }
    }

    // cross-lane reduce over the 4 lk-groups only (offsets 16, 32)
#pragma unroll
    for (int off = 16; off < 64; off <<= 1)
#pragma unroll
        for (int it = 0; it < 4; ++it) {
            es[it] += __shfl_xor(es[it], off, 64);
            ps[it] += __shfl_xor(ps[it], off, 64);
            np[it] += __shfl_xor(np[it], off, 64);
        }
    if (lk == 0) {
#pragma unroll
        for (int it = 0; it < 4; ++it) {
            const int rl = wr * 64 + it * 16 + lr;
            redL[wc][rl][0] = es[it];
            redL[wc][rl][1] = ps[it];
            redL[wc][rl][2] = np[it];
        }
    }
    __syncthreads();
    if (t < TT) {   // fold the 2 col-halves; one float4 per (row, cs)
        f32x4 v;
        v[0] = redL[0][t][0] + redL[1][t][0];
        v[1] = redL[0][t][1] + redL[1][t][1];
        v[2] = redL[0][t][2] + redL[1][t][2];
        v[3] = 0.f;
        partials[(size_t)(ib + t) * NT + cs] = v;   // [row][cs][4] layout
    }
}

// ---- pass 2: per-row loss (contiguous float4 reads) + reduce + atomic -------
__global__ __launch_bounds__(256) void final_kernel(
    const f32x4* __restrict__ partials, float* __restrict__ out)
{
    const int row = blockIdx.x * 256 + threadIdx.x;
    float es = 0.f, ps = 0.f, np = 0.f;
#pragma unroll
    for (int cs = 0; cs < NT; ++cs) {
        const f32x4 v = partials[(size_t)row * NT + cs];
        es += v[0]; ps += v[1]; np += v[2];
    }
    const float lse = logf(es);
    float c = -(ps - np * lse) / ((np + 1e-5f) * (float)NB);
#pragma unroll
    for (int off = 1; off < 64; off <<= 1) c += __shfl_xor(c, off, 64);
    __shared__ float sred[4];
    if ((threadIdx.x & 63) == 0) sred[threadIdx.x >> 6] = c;
    __syncthreads();
    if (threadIdx.x == 0) atomicAdd(out, sred[0] + sred[1] + sred[2] + sred[3]);
}

extern "C" void kernel_launch(void* const* d_in, const int* in_sizes, int n_in,
                              void* d_out, int out_size, void* d_ws, size_t ws_size,
                              hipStream_t stream) {
    const float* features = (const float*)d_in[0];
    const int*   labels   = (const int*)d_in[1];
    float* out = (float*)d_out;
    f32x4* partials = (f32x4*)d_ws;    // 4096*16*16 B = 1 MB

    supcon_mfma<<<NT * NT, 512, 0, stream>>>(features, labels, partials, out);
    final_kernel<<<NB / 256, 256, 0, stream>>>(partials, out);
}

// Round 14
// 19.303 us; speedup vs baseline: 1.0464x; 1.0464x over previous
//
#include <hip/hip_runtime.h>
#include <math.h>

#define NB 4096
#define ND 128
#define TT 256        // tile size; K = ND = 128 staged whole
#define NT (NB / TT)  // 16 tiles per dimension; grid = 256 = 1 block/CU

typedef __bf16 bf16x8 __attribute__((ext_vector_type(8)));
typedef float  f32x4  __attribute__((ext_vector_type(4)));

// ---- pass 1: fused normalize + 256x256 LDS sim-tile + MFMA + stats ----------
// R12 structure (verified best): 16 waves (1024 thr), wr = wid>>1 (8 x 32
// i-rows, it=2), wc = wid&1 (2 x 128 j-cols, jt=8).
// Each block re-normalizes its two row-tiles f32->bf16 while staging to LDS
// (deterministic recompute; no fnb buffer, no extra dispatch).
// LDS layout (16B chunks): (row, c16) -> slot row*16 + (c16 ^ (row&15)).
// Swapped MFMA operands: D col (lane&15) = i index -> stats accumulate
// in-thread; cross-lane reduce = offsets 16/32 only.
__global__ __launch_bounds__(1024) void supcon_mfma(
    const float* __restrict__ f, const int* __restrict__ labels,
    float* __restrict__ partials, float* __restrict__ out)
{
    __shared__ __align__(16) __bf16 At[TT * ND];   // 64 KB (i rows)
    __shared__ __align__(16) __bf16 Bt[TT * ND];   // 64 KB (j rows)
    __shared__ float redL[2][TT][3];               // 6 KB

    const int t    = threadIdx.x;
    const int lane = t & 63;
    const int wid  = t >> 6;            // 0..15
    const int wr   = wid >> 1;          // 0..7 : i rows wr*32 .. +32
    const int wc   = wid & 1;           // 0..1 : j cols wc*128 .. +128
    const int bi   = blockIdx.x >> 4;   // i tile 0..15
    const int cs   = blockIdx.x & 15;   // j tile 0..15
    const int lr   = lane & 15;
    const int lk   = lane >> 4;
    const int ib   = bi * TT;
    const int jb   = cs * TT;

    if (blockIdx.x == 0 && t == 0) out[0] = 0.f;   // target of final's atomics

    // ---- stage + normalize both tiles (f32 -> bf16, XOR-swizzled) -----------
    // A and B loads interleaved per iteration for memory-level parallelism.
    {
        const int c16  = t & 15;        // 16B-chunk index within row
        const int rloc = t >> 4;        // 0..63
        const float* gA = f + (size_t)ib * ND;
        const float* gB = f + (size_t)jb * ND;
#pragma unroll
        for (int p = 0; p < 4; ++p) {
            const int row = p * 64 + rloc;
            const float4 alo = *reinterpret_cast<const float4*>(gA + row * ND + c16 * 8);
            const float4 ahi = *reinterpret_cast<const float4*>(gA + row * ND + c16 * 8 + 4);
            const float4 blo = *reinterpret_cast<const float4*>(gB + row * ND + c16 * 8);
            const float4 bhi = *reinterpret_cast<const float4*>(gB + row * ND + c16 * 8 + 4);

            float ssa = alo.x*alo.x + alo.y*alo.y + alo.z*alo.z + alo.w*alo.w
                      + ahi.x*ahi.x + ahi.y*ahi.y + ahi.z*ahi.z + ahi.w*ahi.w;
            float ssb = blo.x*blo.x + blo.y*blo.y + blo.z*blo.z + blo.w*blo.w
                      + bhi.x*bhi.x + bhi.y*bhi.y + bhi.z*bhi.z + bhi.w*bhi.w;
#pragma unroll
            for (int off = 1; off < 16; off <<= 1) {
                ssa += __shfl_xor(ssa, off, 64);
                ssb += __shfl_xor(ssb, off, 64);
            }
            const float inva = 1.0f / fmaxf(sqrtf(ssa), 1e-12f);
            const float invb = 1.0f / fmaxf(sqrtf(ssb), 1e-12f);
            bf16x8 oa, ob;
            oa[0] = (__bf16)(alo.x * inva); oa[1] = (__bf16)(alo.y * inva);
            oa[2] = (__bf16)(alo.z * inva); oa[3] = (__bf16)(alo.w * inva);
            oa[4] = (__bf16)(ahi.x * inva); oa[5] = (__bf16)(ahi.y * inva);
            oa[6] = (__bf16)(ahi.z * inva); oa[7] = (__bf16)(ahi.w * inva);
            ob[0] = (__bf16)(blo.x * invb); ob[1] = (__bf16)(blo.y * invb);
            ob[2] = (__bf16)(blo.z * invb); ob[3] = (__bf16)(blo.w * invb);
            ob[4] = (__bf16)(bhi.x * invb); ob[5] = (__bf16)(bhi.y * invb);
            ob[6] = (__bf16)(bhi.z * invb); ob[7] = (__bf16)(bhi.w * invb);
            const int dst = (row * 16 + (c16 ^ (row & 15))) * 8;
            *reinterpret_cast<bf16x8*>(&At[dst]) = oa;
            *reinterpret_cast<bf16x8*>(&Bt[dst]) = ob;
        }
    }

    // my i indices / labels (overlap staging latency)
    int ig[2], labi[2];
#pragma unroll
    for (int it = 0; it < 2; ++it) {
        ig[it]   = ib + wr * 32 + it * 16 + lr;   // D col = lane&15
        labi[it] = labels[ig[it]];
    }

    __syncthreads();

    // preload i-side fragments (MFMA B operand)
    bf16x8 bfr[2][4];
#pragma unroll
    for (int it = 0; it < 2; ++it)
#pragma unroll
        for (int ks = 0; ks < 4; ++ks) {
            const int row = wr * 32 + it * 16 + lr;
            bfr[it][ks] = *reinterpret_cast<const bf16x8*>(
                &At[(row * 16 + ((ks * 4 + lk) ^ lr)) * 8]);
        }

    float es[2] = {}, ps[2] = {}, np[2] = {};

#pragma unroll
    for (int jt = 0; jt < 8; ++jt) {
        // j-side fragments (MFMA A operand)
        bf16x8 af[4];
#pragma unroll
        for (int ks = 0; ks < 4; ++ks) {
            const int row = wc * 128 + jt * 16 + lr;
            af[ks] = *reinterpret_cast<const bf16x8*>(
                &Bt[(row * 16 + ((ks * 4 + lk) ^ lr)) * 8]);
        }
        f32x4 acc[2] = {};
#pragma unroll
        for (int ks = 0; ks < 4; ++ks)
#pragma unroll
            for (int it = 0; it < 2; ++it)
                acc[it] = __builtin_amdgcn_mfma_f32_16x16x32_bf16(
                    af[ks], bfr[it][ks], acc[it], 0, 0, 0);

        // j labels for this 16-tile: contiguous int4 per lk group
        const int jg0 = jb + wc * 128 + jt * 16 + lk * 4;   // D row = lk*4 + r
        const int4 lj4 = *reinterpret_cast<const int4*>(&labels[jg0]);
        const int lj[4] = {lj4.x, lj4.y, lj4.z, lj4.w};

        // epilogue: D[row = j-local = lk*4+r][col = i-local = lr]
        if (bi == cs) {   // block-uniform branch: only diagonal blocks see self
#pragma unroll
            for (int it = 0; it < 2; ++it)
#pragma unroll
                for (int r = 0; r < 4; ++r) {
                    const int   jgv  = jg0 + r;
                    const float s    = acc[it][r];
                    const float e    = __expf(s);
                    const bool  self = (jgv == ig[it]);
                    const bool  pos  = (lj[r] == labi[it]) && !self;
                    es[it] += self ? 0.f : e;
                    ps[it] += pos ? s : 0.f;
                    np[it] += pos ? 1.f : 0.f;
                }
        } else {          // off-diagonal: no self-pair possible
#pragma unroll
            for (int it = 0; it < 2; ++it)
#pragma unroll
                for (int r = 0; r < 4; ++r) {
                    const float s   = acc[it][r];
                    const bool  pos = (lj[r] == labi[it]);
                    es[it] += __expf(s);
                    ps[it] += pos ? s : 0.f;
                    np[it] += pos ? 1.f : 0.f;
                }
        }
    }

    // cross-lane reduce over the 4 lk-groups only (offsets 16, 32)
#pragma unroll
    for (int off = 16; off < 64; off <<= 1)
#pragma unroll
        for (int it = 0; it < 2; ++it) {
            es[it] += __shfl_xor(es[it], off, 64);
            ps[it] += __shfl_xor(ps[it], off, 64);
            np[it] += __shfl_xor(np[it], off, 64);
        }
    if (lk == 0) {
#pragma unroll
        for (int it = 0; it < 2; ++it) {
            const int rl = wr * 32 + it * 16 + lr;
            redL[wc][rl][0] = es[it];
            redL[wc][rl][1] = ps[it];
            redL[wc][rl][2] = np[it];
        }
    }
    __syncthreads();
    if (t < TT) {   // fold the 2 col-halves; one deterministic writer per (cs,row)
        float* p = partials + ((size_t)cs * NB + ib + t) * 3;
        p[0] = redL[0][t][0] + redL[1][t][0];
        p[1] = redL[0][t][1] + redL[1][t][1];
        p[2] = redL[0][t][2] + redL[1][t][2];
    }
}

// ---- pass 2: per-row loss + block-level reduce + atomic to out --------------
__global__ __launch_bounds__(256) void final_kernel(
    const float* __restrict__ partials, float* __restrict__ out)
{
    const int row = blockIdx.x * 256 + threadIdx.x;
    float es = 0.f, ps = 0.f, np = 0.f;
#pragma unroll
    for (int cs = 0; cs < NT; ++cs) {
        const float* p = partials + ((size_t)cs * NB + row) * 3;
        es += p[0]; ps += p[1]; np += p[2];
    }
    const float lse = logf(es);
    float c = -(ps - np * lse) / ((np + 1e-5f) * (float)NB);
#pragma unroll
    for (int off = 1; off < 64; off <<= 1) c += __shfl_xor(c, off, 64);
    __shared__ float sred[4];
    if ((threadIdx.x & 63) == 0) sred[threadIdx.x >> 6] = c;
    __syncthreads();
    if (threadIdx.x == 0) atomicAdd(out, sred[0] + sred[1] + sred[2] + sred[3]);
}

extern "C" void kernel_launch(void* const* d_in, const int* in_sizes, int n_in,
                              void* d_out, int out_size, void* d_ws, size_t ws_size,
                              hipStream_t stream) {
    const float* features = (const float*)d_in[0];
    const int*   labels   = (const int*)d_in[1];
    float* out = (float*)d_out;
    float* partials = (float*)d_ws;    // 16*4096*3*4 = 768 KB

    supcon_mfma<<<NT * NT, 1024, 0, stream>>>(features, labels, partials, out);
    final_kernel<<<NB / 256, 256, 0, stream>>>(partials, out);
}

// Round 15
// 18.726 us; speedup vs baseline: 1.0786x; 1.0308x over previous
//
#include <hip/hip_runtime.h>
#include <math.h>

#define NB 4096
#define ND 128
#define TT 256        // tile size; K = ND = 128 staged whole
#define NT (NB / TT)  // 16 tiles per dimension; grid = 256 = 1 block/CU

typedef __bf16 bf16x8 __attribute__((ext_vector_type(8)));
typedef float  f32x4  __attribute__((ext_vector_type(4)));

// ---- pass 1: fused normalize + 256x256 LDS sim-tile + MFMA + stats ----------
// Verified-optimal configuration (R12): 16 waves (1024 thr), wr = wid>>1
// (8 x 32 i-rows, it=2), wc = wid&1 (2 x 128 j-cols, jt=8).
// Each block re-normalizes its two row-tiles f32->bf16 while staging to LDS
// (deterministic recompute; no fnb buffer, no extra dispatch boundary).
// LDS layout (16B chunks): (row, c16) -> slot row*16 + (c16 ^ (row&15))
//   -> conflict-free on both the staging write and the fragment read.
// Swapped MFMA operands: acc = mfma(j_frag, i_frag) so D col (lane&15) = i
// index -> row stats accumulate in-thread; cross-lane reduce = offsets 16/32.
// Measured-rejected alternatives: it=4@1024thr spills (R9); 8 waves can't
// hide DS latency (R13); diagonal-branch + interleaved staging neutral (R14).
__global__ __launch_bounds__(1024) void supcon_mfma(
    const float* __restrict__ f, const int* __restrict__ labels,
    float* __restrict__ partials, float* __restrict__ out)
{
    __shared__ __align__(16) __bf16 At[TT * ND];   // 64 KB (i rows)
    __shared__ __align__(16) __bf16 Bt[TT * ND];   // 64 KB (j rows)
    __shared__ float redL[2][TT][3];               // 6 KB

    const int t    = threadIdx.x;
    const int lane = t & 63;
    const int wid  = t >> 6;            // 0..15
    const int wr   = wid >> 1;          // 0..7 : i rows wr*32 .. +32
    const int wc   = wid & 1;           // 0..1 : j cols wc*128 .. +128
    const int bi   = blockIdx.x >> 4;   // i tile 0..15
    const int cs   = blockIdx.x & 15;   // j tile 0..15
    const int lr   = lane & 15;
    const int lk   = lane >> 4;
    const int ib   = bi * TT;
    const int jb   = cs * TT;

    if (blockIdx.x == 0 && t == 0) out[0] = 0.f;   // target of final's atomics

    // ---- stage + normalize both tiles (f32 -> bf16, XOR-swizzled) -----------
    {
        const int c16  = t & 15;        // 16B-chunk index within row
        const int rloc = t >> 4;        // 0..63
        const float* gA = f + (size_t)ib * ND;
        const float* gB = f + (size_t)jb * ND;
#pragma unroll
        for (int s = 0; s < 2; ++s) {
            const float* g = s ? gB : gA;
            __bf16*      T = s ? Bt : At;
#pragma unroll
            for (int p = 0; p < 4; ++p) {
                const int row = p * 64 + rloc;
                const float4 lo = *reinterpret_cast<const float4*>(g + row * ND + c16 * 8);
                const float4 hi = *reinterpret_cast<const float4*>(g + row * ND + c16 * 8 + 4);
                float ss = lo.x*lo.x + lo.y*lo.y + lo.z*lo.z + lo.w*lo.w
                         + hi.x*hi.x + hi.y*hi.y + hi.z*hi.z + hi.w*hi.w;
#pragma unroll
                for (int off = 1; off < 16; off <<= 1) ss += __shfl_xor(ss, off, 64);
                const float inv = 1.0f / fmaxf(sqrtf(ss), 1e-12f);
                bf16x8 o;
                o[0] = (__bf16)(lo.x * inv); o[1] = (__bf16)(lo.y * inv);
                o[2] = (__bf16)(lo.z * inv); o[3] = (__bf16)(lo.w * inv);
                o[4] = (__bf16)(hi.x * inv); o[5] = (__bf16)(hi.y * inv);
                o[6] = (__bf16)(hi.z * inv); o[7] = (__bf16)(hi.w * inv);
                *reinterpret_cast<bf16x8*>(&T[(row * 16 + (c16 ^ (row & 15))) * 8]) = o;
            }
        }
    }

    // my i indices / labels (overlap staging latency)
    int ig[2], labi[2];
#pragma unroll
    for (int it = 0; it < 2; ++it) {
        ig[it]   = ib + wr * 32 + it * 16 + lr;   // D col = lane&15
        labi[it] = labels[ig[it]];
    }

    __syncthreads();

    // preload i-side fragments (MFMA B operand)
    bf16x8 bfr[2][4];
#pragma unroll
    for (int it = 0; it < 2; ++it)
#pragma unroll
        for (int ks = 0; ks < 4; ++ks) {
            const int row = wr * 32 + it * 16 + lr;
            bfr[it][ks] = *reinterpret_cast<const bf16x8*>(
                &At[(row * 16 + ((ks * 4 + lk) ^ lr)) * 8]);
        }

    float es[2] = {}, ps[2] = {}, np[2] = {};

#pragma unroll
    for (int jt = 0; jt < 8; ++jt) {
        // j-side fragments (MFMA A operand)
        bf16x8 af[4];
#pragma unroll
        for (int ks = 0; ks < 4; ++ks) {
            const int row = wc * 128 + jt * 16 + lr;
            af[ks] = *reinterpret_cast<const bf16x8*>(
                &Bt[(row * 16 + ((ks * 4 + lk) ^ lr)) * 8]);
        }
        f32x4 acc[2] = {};
#pragma unroll
        for (int ks = 0; ks < 4; ++ks)
#pragma unroll
            for (int it = 0; it < 2; ++it)
                acc[it] = __builtin_amdgcn_mfma_f32_16x16x32_bf16(
                    af[ks], bfr[it][ks], acc[it], 0, 0, 0);

        // j labels for this 16-tile: contiguous int4 per lk group
        const int jg0 = jb + wc * 128 + jt * 16 + lk * 4;   // D row = lk*4 + r
        const int4 lj4 = *reinterpret_cast<const int4*>(&labels[jg0]);
        const int lj[4] = {lj4.x, lj4.y, lj4.z, lj4.w};

        // epilogue: D[row = j-local = lk*4+r][col = i-local = lr]
#pragma unroll
        for (int it = 0; it < 2; ++it)
#pragma unroll
            for (int r = 0; r < 4; ++r) {
                const int   jgv  = jg0 + r;
                const float s    = acc[it][r];
                const float e    = __expf(s);
                const bool  self = (jgv == ig[it]);
                const bool  pos  = (lj[r] == labi[it]) && !self;
                es[it] += self ? 0.f : e;
                ps[it] += pos ? s : 0.f;
                np[it] += pos ? 1.f : 0.f;
            }
    }

    // cross-lane reduce over the 4 lk-groups only (offsets 16, 32)
#pragma unroll
    for (int off = 16; off < 64; off <<= 1)
#pragma unroll
        for (int it = 0; it < 2; ++it) {
            es[it] += __shfl_xor(es[it], off, 64);
            ps[it] += __shfl_xor(ps[it], off, 64);
            np[it] += __shfl_xor(np[it], off, 64);
        }
    if (lk == 0) {
#pragma unroll
        for (int it = 0; it < 2; ++it) {
            const int rl = wr * 32 + it * 16 + lr;
            redL[wc][rl][0] = es[it];
            redL[wc][rl][1] = ps[it];
            redL[wc][rl][2] = np[it];
        }
    }
    __syncthreads();
    if (t < TT) {   // fold the 2 col-halves; one deterministic writer per (cs,row)
        float* p = partials + ((size_t)cs * NB + ib + t) * 3;
        p[0] = redL[0][t][0] + redL[1][t][0];
        p[1] = redL[0][t][1] + redL[1][t][1];
        p[2] = redL[0][t][2] + redL[1][t][2];
    }
}

// ---- pass 2: per-row loss + block-level reduce + atomic to out --------------
__global__ __launch_bounds__(256) void final_kernel(
    const float* __restrict__ partials, float* __restrict__ out)
{
    const int row = blockIdx.x * 256 + threadIdx.x;
    float es = 0.f, ps = 0.f, np = 0.f;
#pragma unroll
    for (int cs = 0; cs < NT; ++cs) {
        const float* p = partials + ((size_t)cs * NB + row) * 3;
        es += p[0]; ps += p[1]; np += p[2];
    }
    const float lse = logf(es);
    float c = -(ps - np * lse) / ((np + 1e-5f) * (float)NB);
#pragma unroll
    for (int off = 1; off < 64; off <<= 1) c += __shfl_xor(c, off, 64);
    __shared__ float sred[4];
    if ((threadIdx.x & 63) == 0) sred[threadIdx.x >> 6] = c;
    __syncthreads();
    if (threadIdx.x == 0) atomicAdd(out, sred[0] + sred[1] + sred[2] + sred[3]);
}

extern "C" void kernel_launch(void* const* d_in, const int* in_sizes, int n_in,
                              void* d_out, int out_size, void* d_ws, size_t ws_size,
                              hipStream_t stream) {
    const float* features = (const float*)d_in[0];
    const int*   labels   = (const int*)d_in[1];
    float* out = (float*)d_out;
    float* partials = (float*)d_ws;    // 16*4096*3*4 = 768 KB

    supcon_mfma<<<NT * NT, 1024, 0, stream>>>(features, labels, partials, out);
    final_kernel<<<NB / 256, 256, 0, stream>>>(partials, out);
}